// Round 1
// baseline (265.270 us; speedup 1.0000x reference)
//
#include <hip/hip_runtime.h>
#include <hip/hip_bf16.h>

// GCN layer: out = relu( (D^-1/2 A D^-1/2) @ (x @ W) ) over channel dim.
// B=16, C=64, S=2048, Fin=Fout=64.
#define B_ 16
#define C_ 64
#define S_ 2048
#define F_ 64
#define SF (S_ * F_)   // 131072, stride between channels

typedef __attribute__((ext_vector_type(8))) short short8;   // 8 bf16 (4 VGPRs) MFMA A/B frag
typedef __attribute__((ext_vector_type(4))) float float4_;  // MFMA C/D frag

__device__ __forceinline__ unsigned short f2bf(float f) {
    // round-to-nearest-even fp32 -> bf16 (inputs are finite; no NaN handling)
    unsigned int u = __builtin_bit_cast(unsigned int, f);
    u += 0x7fffu + ((u >> 16) & 1u);
    return (unsigned short)(u >> 16);
}

// ---------------------------------------------------------------------------
// Prep: norm_adj = adj * rsqrt(rowsum)[c] * rsqrt(rowsum)[d]  -> bf16 [c][d]
//       wT[o][f] = bf16(weight[f][o])  (transposed so B-frag reads are contiguous)
// ---------------------------------------------------------------------------
__global__ void gcn_prep(const float* __restrict__ adj, const float* __restrict__ wgt,
                         unsigned short* __restrict__ nadj, unsigned short* __restrict__ wT)
{
    __shared__ float dis[C_];
    const int t = threadIdx.x;
    if (t < C_) {
        float s = 0.f;
        for (int d = 0; d < C_; ++d) s += adj[t * C_ + d];
        dis[t] = rsqrtf(s);
    }
    __syncthreads();
    for (int i = t; i < C_ * C_; i += 256) {
        const int c = i >> 6, d = i & 63;
        nadj[i] = f2bf(adj[i] * dis[c] * dis[d]);
        // wgt[f=c][o=d] -> wT[o][f]
        wT[d * F_ + c] = f2bf(wgt[i]);
    }
}

// ---------------------------------------------------------------------------
// Main: one block = (b, 8 consecutive s). One wave = one s value.
// Stage 1: support[d][o] = x[b,d,s,:] @ W      (A = x rows, B = W)
// Stage 2: out[c][o]     = A_norm @ support    (A = norm_adj, B = support^T via LDS)
// support transposed through wave-local XOR-swizzled LDS (no barrier needed).
// ---------------------------------------------------------------------------
__global__ __launch_bounds__(512) void gcn_main(
    const float* __restrict__ x,
    const unsigned short* __restrict__ nadj,
    const unsigned short* __restrict__ wT,
    float* __restrict__ out)
{
    // supT[n][d] with n = wave*64 + o  (bf16), inner index XOR-swizzled:
    // elem = n*64 + (d ^ ((n&7)<<3))  -> 2-way max bank aliasing (free)
    __shared__ unsigned short supT[8 * 64 * 64];  // 64 KB

    const int tid  = threadIdx.x;
    const int w    = tid >> 6;          // wave id 0..7  == sb (s within tile)
    const int l    = tid & 63;
    const int lrow = l & 15;            // fragment row/col
    const int lgrp = l >> 4;            // 0..3 k-group

    const int b  = blockIdx.x >> 8;     // 256 s-tiles per b
    const int st = blockIdx.x & 255;
    const int s  = st * 8 + w;          // this wave's s

    // ---- W fragments (B-operand, stage 1): wf[otile][kstep]
    short8 wf[4][2];
#pragma unroll
    for (int ot = 0; ot < 4; ++ot)
#pragma unroll
        for (int ks = 0; ks < 2; ++ks)
            wf[ot][ks] = *(const short8*)(wT + (ot * 16 + lrow) * 64 + ks * 32 + lgrp * 8);

    // ---- Stage 1: load x A-fragments (all 64 d), convert fp32->bf16
    const float* xb = x + (size_t)b * C_ * SF + (size_t)s * F_;
    short8 af[4][2];
#pragma unroll
    for (int dt = 0; dt < 4; ++dt) {
        const float* xr = xb + (size_t)(dt * 16 + lrow) * SF;
#pragma unroll
        for (int ks = 0; ks < 2; ++ks) {
            float4_ u0 = *(const float4_*)(xr + ks * 32 + lgrp * 8);
            float4_ u1 = *(const float4_*)(xr + ks * 32 + lgrp * 8 + 4);
            short8 a;
#pragma unroll
            for (int j = 0; j < 4; ++j) {
                a[j]     = (short)f2bf(u0[j]);
                a[4 + j] = (short)f2bf(u1[j]);
            }
            af[dt][ks] = a;
        }
    }

    // ---- Stage 1 MFMAs: support[d][o], write transposed+swizzled to LDS
#pragma unroll
    for (int dt = 0; dt < 4; ++dt) {
        const int dbase = dt * 16 + lgrp * 4;   // C-frag rows = d
#pragma unroll
        for (int ot = 0; ot < 4; ++ot) {
            float4_ acc = {0.f, 0.f, 0.f, 0.f};
            acc = __builtin_amdgcn_mfma_f32_16x16x32_bf16(af[dt][0], wf[ot][0], acc, 0, 0, 0);
            acc = __builtin_amdgcn_mfma_f32_16x16x32_bf16(af[dt][1], wf[ot][1], acc, 0, 0, 0);
            const int n = w * 64 + ot * 16 + lrow;          // C-frag col = o
            const int e = n * 64 + (dbase ^ ((n & 7) << 3));
            uint2 pk;
            pk.x = (unsigned)f2bf(acc[0]) | ((unsigned)f2bf(acc[1]) << 16);
            pk.y = (unsigned)f2bf(acc[2]) | ((unsigned)f2bf(acc[3]) << 16);
            *(uint2*)(supT + e) = pk;   // 4 consecutive d, 8B store
        }
    }

    // ---- Stage 2: B-fragments from LDS (wave-local: only our own writes; the
    // compiler's lgkmcnt waits order the within-wave RAW, no __syncthreads).
    short8 bfr[4][2];
#pragma unroll
    for (int ot = 0; ot < 4; ++ot) {
        const int n = w * 64 + ot * 16 + lrow;
#pragma unroll
        for (int ks = 0; ks < 2; ++ks) {
            const int e = n * 64 + ((ks * 32 + lgrp * 8) ^ ((n & 7) << 3));
            bfr[ot][ks] = *(const short8*)(supT + e);
        }
    }

    float* ob = out + (size_t)b * C_ * SF + (size_t)s * F_;
#pragma unroll
    for (int ct = 0; ct < 4; ++ct) {
        short8 an[2];
#pragma unroll
        for (int ks = 0; ks < 2; ++ks)
            an[ks] = *(const short8*)(nadj + (ct * 16 + lrow) * 64 + ks * 32 + lgrp * 8);
        const int cb = ct * 16 + lgrp * 4;      // C-frag rows = c
#pragma unroll
        for (int ot = 0; ot < 4; ++ot) {
            float4_ acc = {0.f, 0.f, 0.f, 0.f};
            acc = __builtin_amdgcn_mfma_f32_16x16x32_bf16(an[0], bfr[ot][0], acc, 0, 0, 0);
            acc = __builtin_amdgcn_mfma_f32_16x16x32_bf16(an[1], bfr[ot][1], acc, 0, 0, 0);
            const int o = ot * 16 + lrow;
#pragma unroll
            for (int i = 0; i < 4; ++i)
                ob[(size_t)(cb + i) * SF + o] = fmaxf(acc[i], 0.f);
        }
    }
}

// ---------------------------------------------------------------------------
extern "C" void kernel_launch(void* const* d_in, const int* in_sizes, int n_in,
                              void* d_out, int out_size, void* d_ws, size_t ws_size,
                              hipStream_t stream) {
    const float* x   = (const float*)d_in[0];
    const float* adj = (const float*)d_in[1];
    const float* wgt = (const float*)d_in[2];
    float* out = (float*)d_out;

    unsigned short* nadj = (unsigned short*)d_ws;      // 4096 bf16
    unsigned short* wT   = nadj + C_ * C_;             // 4096 bf16

    gcn_prep<<<1, 256, 0, stream>>>(adj, wgt, nadj, wT);

    dim3 grid(B_ * (S_ / 8));   // 4096 blocks: (b, s-tile of 8)
    gcn_main<<<grid, 512, 0, stream>>>(x, nadj, wT, out);
}

// Round 2
// 253.493 us; speedup vs baseline: 1.0465x; 1.0465x over previous
//
#include <hip/hip_runtime.h>
#include <hip/hip_bf16.h>

// GCN layer: out = relu( (D^-1/2 A D^-1/2) @ (x @ W) ) over channel dim.
// B=16, C=64, S=2048, Fin=Fout=64.
#define B_ 16
#define C_ 64
#define S_ 2048
#define F_ 64
#define SF (S_ * F_)   // 131072, stride between channels

typedef __attribute__((ext_vector_type(8))) short short8;   // 8 bf16 (4 VGPRs) MFMA A/B frag
typedef __attribute__((ext_vector_type(4))) float float4_;  // MFMA C/D frag

// XOR-swizzle: spread 128B-stride rows across banks; keeps 8-elem groups contiguous
#define SWZ(row, col) ((col) ^ (((row) & 7) << 3))

__device__ __forceinline__ unsigned short f2bf(float f) {
    // round-to-nearest-even fp32 -> bf16 (inputs finite; no NaN handling)
    unsigned int u = __builtin_bit_cast(unsigned int, f);
    u += 0x7fffu + ((u >> 16) & 1u);
    return (unsigned short)(u >> 16);
}

// ---------------------------------------------------------------------------
// Prep: norm_adj = adj * rsqrt(rowsum)[c] * rsqrt(rowsum)[d]  -> bf16 [c][d]
//       wT[o][f] = bf16(weight[f][o])
// ---------------------------------------------------------------------------
__global__ void gcn_prep(const float* __restrict__ adj, const float* __restrict__ wgt,
                         unsigned short* __restrict__ nadj, unsigned short* __restrict__ wT)
{
    __shared__ float dis[C_];
    const int t = threadIdx.x;
    if (t < C_) {
        float s = 0.f;
        for (int d = 0; d < C_; ++d) s += adj[t * C_ + d];
        dis[t] = rsqrtf(s);
    }
    __syncthreads();
    for (int i = t; i < C_ * C_; i += 256) {
        const int c = i >> 6, d = i & 63;
        nadj[i] = f2bf(adj[i] * dis[c] * dis[d]);
        wT[d * F_ + c] = f2bf(wgt[i]);   // wgt[f=c][o=d] -> wT[o][f]
    }
}

// ---------------------------------------------------------------------------
// Main: one block = (b, 8 consecutive s); one wave = one s.
// Stage 1: sup[d][o] = x[b,d,s,:] @ W        (A = x rows, B = W)
// Stage 2: out[c][o] = A_norm @ sup, computed TRANSPOSED:
//          mfma(A = sup^T frags from LDS, B = nadj rows) -> lane holds
//          out[c=lrow][o=lgrp*4+i]  => contiguous float4 stores.
// ---------------------------------------------------------------------------
__global__ __launch_bounds__(512, 4) void gcn_main(
    const float* __restrict__ x,
    const unsigned short* __restrict__ nadj,
    const unsigned short* __restrict__ wT,
    float* __restrict__ out)
{
    __shared__ __align__(16) unsigned short lds_nadj[C_ * C_];   // 8 KB, swizzled
    __shared__ __align__(16) unsigned short lds_wT[F_ * F_];     // 8 KB, swizzled
    __shared__ __align__(16) unsigned short supT[8 * 16 * F_];   // 16 KB: per-wave 16 o-rows x 64 d

    const int tid  = threadIdx.x;
    const int w    = tid >> 6;          // wave id 0..7  == s within tile
    const int l    = tid & 63;
    const int lrow = l & 15;
    const int lgrp = l >> 4;            // 0..3

    // ---- cooperative fill of nadj/wT into swizzled LDS (16B per thread each)
    {
        const int fc = tid >> 3;          // row 0..63
        const int fd = (tid & 7) * 8;     // col base
        *(short8*)(lds_nadj + fc * 64 + SWZ(fc, fd)) = *(const short8*)(nadj + fc * 64 + fd);
        *(short8*)(lds_wT  + fc * 64 + SWZ(fc, fd)) = *(const short8*)(wT  + fc * 64 + fd);
    }
    __syncthreads();

    const int b  = blockIdx.x >> 8;     // 256 s-tiles per b
    const int st = blockIdx.x & 255;
    const int s  = st * 8 + w;

    // ---- load x A-fragments for all 64 channels (fp32 -> bf16)
    const float* xb = x + (size_t)b * C_ * SF + (size_t)s * F_;
    short8 af[4][2];
#pragma unroll
    for (int dt = 0; dt < 4; ++dt) {
        const float* xr = xb + (size_t)(dt * 16 + lrow) * SF;
#pragma unroll
        for (int ks = 0; ks < 2; ++ks) {
            float4_ u0 = *(const float4_*)(xr + ks * 32 + lgrp * 8);
            float4_ u1 = *(const float4_*)(xr + ks * 32 + lgrp * 8 + 4);
            short8 a;
#pragma unroll
            for (int j = 0; j < 4; ++j) {
                a[j]     = (short)f2bf(u0[j]);
                a[4 + j] = (short)f2bf(u1[j]);
            }
            af[dt][ks] = a;
        }
    }

    unsigned short* myT = supT + w * (16 * F_);
    float* ob = out + (size_t)b * C_ * SF + (size_t)s * F_;

#pragma unroll
    for (int ot = 0; ot < 4; ++ot) {
        // W fragments for this o-tile (B-operand, stage 1)
        const int orow = ot * 16 + lrow;
        short8 wf0 = *(const short8*)(lds_wT + orow * 64 + SWZ(lrow, lgrp * 8));
        short8 wf1 = *(const short8*)(lds_wT + orow * 64 + SWZ(lrow, 32 + lgrp * 8));

        // Stage 1: sup[d][o] for o in this tile; write transposed+swizzled
#pragma unroll
        for (int dt = 0; dt < 4; ++dt) {
            float4_ s1 = {0.f, 0.f, 0.f, 0.f};
            s1 = __builtin_amdgcn_mfma_f32_16x16x32_bf16(af[dt][0], wf0, s1, 0, 0, 0);
            s1 = __builtin_amdgcn_mfma_f32_16x16x32_bf16(af[dt][1], wf1, s1, 0, 0, 0);
            const int dbase = dt * 16 + lgrp * 4;     // C-frag rows = d
            uint2 pk;                                  // lane's col = o = orow
            pk.x = (unsigned)f2bf(s1[0]) | ((unsigned)f2bf(s1[1]) << 16);
            pk.y = (unsigned)f2bf(s1[2]) | ((unsigned)f2bf(s1[3]) << 16);
            *(uint2*)(myT + lrow * 64 + SWZ(lrow, dbase)) = pk;
        }

        // sup^T fragments (A-operand, stage 2): row = o_local = lrow, k = d
        short8 bf0 = *(const short8*)(myT + lrow * 64 + SWZ(lrow, lgrp * 8));
        short8 bf1 = *(const short8*)(myT + lrow * 64 + SWZ(lrow, 32 + lgrp * 8));

        // Stage 2: out[c][o] = sum_d nadj[c][d] sup[d][o], transposed compute
#pragma unroll
        for (int ct = 0; ct < 4; ++ct) {
            const int crow = ct * 16 + lrow;
            short8 an0 = *(const short8*)(lds_nadj + crow * 64 + SWZ(lrow, lgrp * 8));
            short8 an1 = *(const short8*)(lds_nadj + crow * 64 + SWZ(lrow, 32 + lgrp * 8));
            float4_ acc = {0.f, 0.f, 0.f, 0.f};
            acc = __builtin_amdgcn_mfma_f32_16x16x32_bf16(bf0, an0, acc, 0, 0, 0);
            acc = __builtin_amdgcn_mfma_f32_16x16x32_bf16(bf1, an1, acc, 0, 0, 0);
            // lane holds out[c=crow][o = ot*16 + lgrp*4 + i], i=0..3 contiguous
            float4_ r;
#pragma unroll
            for (int i = 0; i < 4; ++i) r[i] = fmaxf(acc[i], 0.f);
            *(float4_*)(ob + (size_t)crow * SF + ot * 16 + lgrp * 4) = r;
        }
    }
}

// ---------------------------------------------------------------------------
extern "C" void kernel_launch(void* const* d_in, const int* in_sizes, int n_in,
                              void* d_out, int out_size, void* d_ws, size_t ws_size,
                              hipStream_t stream) {
    const float* x   = (const float*)d_in[0];
    const float* adj = (const float*)d_in[1];
    const float* wgt = (const float*)d_in[2];
    float* out = (float*)d_out;

    unsigned short* nadj = (unsigned short*)d_ws;      // 4096 bf16
    unsigned short* wT   = nadj + C_ * C_;             // 4096 bf16

    gcn_prep<<<1, 256, 0, stream>>>(adj, wgt, nadj, wT);

    dim3 grid(B_ * (S_ / 8));   // 4096 blocks: (b, s-tile of 8)
    gcn_main<<<grid, 512, 0, stream>>>(x, nadj, wT, out);
}